// Round 7
// baseline (313.257 us; speedup 1.0000x reference)
//
#include <hip/hip_runtime.h>
#include <math.h>

// Problem constants
#define N_IMG 128
#define IC 8
#define IH 128
#define IW 128
#define OC 64
#define OH 126
#define OW 126
#define NG 16
#define CPG 4          // channels per group
#define PH 31
#define PW 31
#define GN_EPS 1e-5f

// edge2: compute 2 consecutive output columns (ow, ow+1) x 4 channels of the
// 3x3 conv for one output row. Stats-only edge work (cols 124-125 / rows
// 124-125). ow must be even (float2 loads are 8B aligned). acc pre-init'd
// with (signed) bias. Weights in LDS [ic][kh][kw][ch], pre-multiplied by
// sgn(gn_w*scale).
__device__ __forceinline__ void edge2(const float* __restrict__ xb,
                                      const float* wlds_,
                                      int oh, int ow,
                                      float acc[2][CPG]) {
#pragma unroll 1
    for (int ic = 0; ic < IC; ic++) {
        const float* xr = xb + ic * (IH * IW) + oh * IW + ow;
        float xv[3][4];
#pragma unroll
        for (int kh = 0; kh < 3; kh++) {
            float2 a = *(const float2*)(xr + kh * IW);
            float2 b = *(const float2*)(xr + kh * IW + 2);
            xv[kh][0] = a.x; xv[kh][1] = a.y;
            xv[kh][2] = b.x; xv[kh][3] = b.y;
        }
        const float* wk = wlds_ + ic * 36;
#pragma unroll
        for (int kh = 0; kh < 3; kh++) {
            float wr[12];
#pragma unroll
            for (int t = 0; t < 12; t++) wr[t] = wk[kh * 12 + t];
#pragma unroll
            for (int ch = 0; ch < CPG; ch++) {
                float w0 = wr[0 * 4 + ch];
                float w1 = wr[1 * 4 + ch];
                float w2 = wr[2 * 4 + ch];
                acc[0][ch] = fmaf(xv[kh][0], w0,
                             fmaf(xv[kh][1], w1,
                             fmaf(xv[kh][2], w2, acc[0][ch])));
                acc[1][ch] = fmaf(xv[kh][1], w0,
                             fmaf(xv[kh][2], w1,
                             fmaf(xv[kh][3], w2, acc[1][ch])));
            }
        }
    }
}

// load6: 6 x-rows x 6 cols into a register buffer (12 vector loads).
__device__ __forceinline__ void load6(const float* __restrict__ p,
                                      float (&buf)[6][6]) {
#pragma unroll
    for (int rr = 0; rr < 6; rr++) {
        float4 f4 = *(const float4*)(p + rr * IW);
        float2 f2 = *(const float2*)(p + rr * IW + 4);
        buf[rr][0] = f4.x; buf[rr][1] = f4.y;
        buf[rr][2] = f4.z; buf[rr][3] = f4.w;
        buf[rr][4] = f2.x; buf[rr][5] = f2.y;
    }
}

// fma36: one ic's full 3x3 conv contribution for the 4x4xCPG output block.
// 576 FMAs, weights read from LDS (wk = wlds + ic*36).
__device__ __forceinline__ void fma36(const float (&xv)[6][6],
                                      const float* wk,
                                      float (&acc)[4][4][CPG]) {
#pragma unroll
    for (int kh = 0; kh < 3; kh++) {
        float wr[12];
#pragma unroll
        for (int t = 0; t < 12; t++) wr[t] = wk[kh * 12 + t];
#pragma unroll
        for (int ch = 0; ch < CPG; ch++) {
            float w0 = wr[0 * 4 + ch];
            float w1 = wr[1 * 4 + ch];
            float w2 = wr[2 * 4 + ch];
#pragma unroll
            for (int rr = 0; rr < 4; rr++) {
#pragma unroll
                for (int j = 0; j < 4; j++) {
                    acc[rr][j][ch] = fmaf(xv[rr + kh][j],     w0,
                                     fmaf(xv[rr + kh][j + 1], w1,
                                     fmaf(xv[rr + kh][j + 2], w2, acc[rr][j][ch])));
                }
            }
        }
    }
}

// One block per (n, group), XCD-swizzled so each XCD owns contiguous images
// (verified: FETCH_SIZE 850MB -> 33MB). Single conv pass; per pool cell ONE
// 4-output-row register block with a FULL 6-row double buffer:
//   iter: load6(ic+1 -> bufB); fma36(bufA, ic); load6(ic+2 -> bufA);
//         fma36(bufB, ic+1)
// Every load has a ~1150-cycle FMA block of cover (round-6 lesson: the 3-row
// prefetch left rows 3-5 exposed -- kh->ch->rr order needs row 3 after only
// ~9 FMAs, so each ic still paid the ~225cy lead-in; VALUBusy stuck at 65%).
// Buffers are statically indexed (A/B named, ic step 2) -- runtime-indexed
// buffers go to scratch.
//
// REGISTER BUDGET: amdgpu_waves_per_eu(2,4) -> 256-VGPR budget (verified
// round 6: VGPR moved 84->92, spill WRITE_SIZE 209->31MB). This version
// needs ~190 VGPR (2 bufs + acc 64 + pm 16); without the attribute the
// allocator pins an 85-VGPR budget and spills (rounds 4-5).
//
// Edge strips: fine-grained edge2 (250 units, 1/thread, no wasted lanes).
// Weights/bias pre-multiplied by sgn(gn_w*scale): pool extreme is a bare
// fmaxf; sum/sumsq per-channel (4 parallel chains).
// out = clamp(rstd*|gn_w*scale|*M + (gn_b - mean*rstd*gn_w)*scale, 0, 1).
__attribute__((amdgpu_waves_per_eu(2, 4)))
__launch_bounds__(256)
__global__ void fused_conv_gn_pool_kernel(const float* __restrict__ x,
                                          const float* __restrict__ conv_w,
                                          const float* __restrict__ conv_b,
                                          const float* __restrict__ gn_w,
                                          const float* __restrict__ gn_b,
                                          const float* __restrict__ scale,
                                          float* __restrict__ out) {
    const int b = blockIdx.x;               // 0..2047 hardware block id
    // XCD-aware swizzle: hw blocks round-robin XCDs by (b % 8); give XCD j
    // the contiguous work range [j*256, (j+1)*256) == images j*16..j*16+15.
    const int wid = ((b & 7) << 8) | (b >> 3);
    const int n = wid >> 4;
    const int g = wid & 15;
    const int tid = threadIdx.x;

    __shared__ float wlds[IC * 3 * 3 * CPG];   // 288 floats, [ic][kh][kw][ch], signed
    __shared__ float red[8];                    // 4 waves x {sum, sumsq}
    __shared__ float stats[2];                  // mean, rstd

    for (int t = tid; t < IC * 3 * 3 * CPG; t += 256) {
        int ch = t & 3;
        int r = t >> 2;                        // ic*9 + kh*3 + kw
        int c = g * CPG + ch;
        float sg = (gn_w[c] * scale[c] >= 0.f) ? 1.f : -1.f;
        wlds[t] = conv_w[c * (IC * 9) + r] * sg;
    }
    float biasS[CPG], sgnf[CPG];
#pragma unroll
    for (int ch = 0; ch < CPG; ch++) {
        int c = g * CPG + ch;
        float sg = (gn_w[c] * scale[c] >= 0.f) ? 1.f : -1.f;
        sgnf[ch] = sg;
        biasS[ch] = conv_b[c] * sg;
    }
    __syncthreads();

    const float* xb = x + (size_t)n * (IC * IH * IW);
    const int CS = IH * IW;                    // channel stride

    float s_ch[CPG];                 // per-channel signed-conv partial sums
    float ss_ch[CPG];                // per-channel sum of squares (4 chains)
#pragma unroll
    for (int ch = 0; ch < CPG; ch++) { s_ch[ch] = 0.f; ss_ch[ch] = 0.f; }
    float pm[4][CPG];                // running extreme per owned pool cell
#pragma unroll
    for (int ci = 0; ci < 4; ci++)
#pragma unroll
        for (int ch = 0; ch < CPG; ch++) pm[ci][ch] = -INFINITY;

    // ---- Main: pool region (conv rows/cols 0..123), one pass ----
#pragma unroll 1
    for (int ci = 0; ci < 4; ci++) {
        int cell = tid + ci * 256;
        if (cell < PH * PW) {
            int ph = cell / PW;
            int pw = cell - ph * PW;
            const int r0 = 4 * ph;             // conv rows r0..r0+3
            const float* xcell = xb + r0 * IW + 4 * pw;

            float acc[4][4][CPG];              // [row][col][ch]
#pragma unroll
            for (int rr = 0; rr < 4; rr++)
#pragma unroll
                for (int j = 0; j < 4; j++)
#pragma unroll
                    for (int ch = 0; ch < CPG; ch++) acc[rr][j][ch] = biasS[ch];

            float bufA[6][6], bufB[6][6];
            load6(xcell, bufA);                // ic=0 (only exposed lead-in)

#pragma unroll 1
            for (int ic = 0; ic < IC; ic += 2) {
                // prefetch ic+1 under ic's FMA block
                load6(xcell + (ic + 1) * CS, bufB);
                fma36(bufA, wlds + ic * 36, acc);
                // prefetch ic+2 under ic+1's FMA block (clamped reload of
                // ic+1 on the last pair: 12 L1-hot loads, avoids a branch)
                load6(xcell + ((ic + 2 < IC) ? ic + 2 : ic + 1) * CS, bufA);
                fma36(bufB, wlds + (ic + 1) * 36, acc);
            }

            // fold into stats + pool extremes (signed domain)
#pragma unroll
            for (int rr = 0; rr < 4; rr++)
#pragma unroll
                for (int j = 0; j < 4; j++)
#pragma unroll
                    for (int ch = 0; ch < CPG; ch++) {
                        float v = acc[rr][j][ch];
                        s_ch[ch] += v;
                        ss_ch[ch] = fmaf(v, v, ss_ch[ch]);
                        pm[ci][ch] = fmaxf(pm[ci][ch], v);
                    }
        }
    }

    // ---- Edges: conv outputs needed for stats only ----
    // 250 fine-grained units, one per thread:
    //   u in [0,124): right edge, row u, cols 124-125
    //   u in [124,250): bottom rows, u2=u-124: oh=124+(u2>=63), col pair
    //   (u2 mod 63)*2 covering cols 0..125
    if (tid < 250) {
        int oh, ow;
        if (tid < 124) {
            oh = tid; ow = 124;
        } else {
            int u2 = tid - 124;
            int hi = (u2 >= 63) ? 1 : 0;
            oh = 124 + hi;
            ow = (u2 - 63 * hi) * 2;
        }
        float acc[2][CPG];
#pragma unroll
        for (int j = 0; j < 2; j++)
#pragma unroll
            for (int ch = 0; ch < CPG; ch++) acc[j][ch] = biasS[ch];
        edge2(xb, wlds, oh, ow, acc);
#pragma unroll
        for (int j = 0; j < 2; j++)
#pragma unroll
            for (int ch = 0; ch < CPG; ch++) {
                float v = acc[j][ch];
                s_ch[ch] += v;
                ss_ch[ch] = fmaf(v, v, ss_ch[ch]);
            }
    }

    // ---- Block reduction for GN stats (restore per-channel sign) ----
    float s = sgnf[0] * s_ch[0] + sgnf[1] * s_ch[1]
            + sgnf[2] * s_ch[2] + sgnf[3] * s_ch[3];
    float ss = ss_ch[0] + ss_ch[1] + ss_ch[2] + ss_ch[3];
#pragma unroll
    for (int off = 32; off > 0; off >>= 1) {
        s  += __shfl_down(s, off, 64);
        ss += __shfl_down(ss, off, 64);
    }
    int wave = tid >> 6;
    if ((tid & 63) == 0) { red[wave] = s; red[4 + wave] = ss; }
    __syncthreads();
    if (tid == 0) {
        float S  = red[0] + red[1] + red[2] + red[3];
        float SS = red[4] + red[5] + red[6] + red[7];
        const float inv_count = 1.f / (float)(CPG * OH * OW);
        float mean = S * inv_count;
        float var = SS * inv_count - mean * mean;
        if (var < 0.f) var = 0.f;
        stats[0] = mean;
        stats[1] = rsqrtf(var + GN_EPS);
    }
    __syncthreads();
    const float mean = stats[0];
    const float rstd = stats[1];

    // Fused affine for the pooled extreme: out = a2*M + b2  (a2 >= 0,
    // M is the signed-domain max, equal to max over window of sgn*v)
    float a2[CPG], b2[CPG];
#pragma unroll
    for (int ch = 0; ch < CPG; ch++) {
        int c = g * CPG + ch;
        float gw = gn_w[c], sc = scale[c];
        a2[ch] = rstd * fabsf(gw * sc);
        b2[ch] = (gn_b[c] - mean * rstd * gw) * sc;
    }

    // ---- Write pooled, clamped output ----
#pragma unroll
    for (int ci = 0; ci < 4; ci++) {
        int cell = tid + ci * 256;
        if (cell < PH * PW) {
            int ph = cell / PW;
            int pw = cell - ph * PW;
#pragma unroll
            for (int ch = 0; ch < CPG; ch++) {
                int c = g * CPG + ch;
                float v = fmaf(a2[ch], pm[ci][ch], b2[ch]);
                v = fminf(fmaxf(v, 0.f), 1.f);
                out[(((size_t)n * OC + c) * PH + ph) * PW + pw] = v;
            }
        }
    }
}

extern "C" void kernel_launch(void* const* d_in, const int* in_sizes, int n_in,
                              void* d_out, int out_size, void* d_ws, size_t ws_size,
                              hipStream_t stream) {
    const float* x      = (const float*)d_in[0];
    const float* conv_w = (const float*)d_in[1];
    const float* conv_b = (const float*)d_in[2];
    const float* gn_w   = (const float*)d_in[3];
    const float* gn_b   = (const float*)d_in[4];
    const float* scale  = (const float*)d_in[5];
    float* out = (float*)d_out;

    dim3 grid(N_IMG * NG);   // one block per (n, group), XCD-swizzled in-kernel
    dim3 block(256);
    hipLaunchKernelGGL(fused_conv_gn_pool_kernel, grid, block, 0, stream,
                       x, conv_w, conv_b, gn_w, gn_b, scale, out);
}